// Round 6
// baseline (404.860 us; speedup 1.0000x reference)
//
#include <hip/hip_runtime.h>
#include <hip/hip_cooperative_groups.h>
#include <math.h>

namespace cgrp = cooperative_groups;

// ---------------------------------------------------------------------------
// NB regression log-posterior, fused single-pass-over-Y design.
//   phase1: sy[n]=sum_g Y, se[n]=sum_g exp(mu+X.beta); cache Y as ushort in
//           LDS (3 of 4 tiles); 20 blocks also do priors + r,cg tables.
//   grid.sync()
//   phase2: dc[n]=log sy - log se; sum nb terms with y from LDS / 1 re-read.
// Tolerance: 2% of ~2.3e9 -> fast transcendentals + 2-term Stirling are safe.
// ---------------------------------------------------------------------------

#define FN_N   1024
#define FN_G   20000
#define FN_C   20      // gene chunks
#define FN_CW4 250     // float4s per chunk (1000 genes)
#define FN_G4  5000    // float4s per beta row
#define FN_SR  8       // rows per slab
#define FN_B   640     // blocks = 20 chunks x 32 slab-groups
#define FN_K   4       // tiles (slabs) per block

__device__ __forceinline__ float fast_rcp(float x) {
    return __builtin_amdgcn_rcpf(x);
}

// Accurate lgamma (priors only; divergent loop is off the hot path).
__device__ __forceinline__ float lgamma_pos(float x) {
    float lp = 0.0f;
    if (x < 8.0f) {
        float p = x;
        x += 1.0f;
        while (x < 8.0f) { p *= x; x += 1.0f; }
        lp = __logf(p);
    }
    float inv  = fast_rcp(x);
    float inv2 = inv * inv;
    float ser = inv * (0.08333333333f + inv2 * (-0.002777777778f + inv2 * 7.936507937e-4f));
    return (x - 0.5f) * __logf(x) - x + 0.9189385332f + ser - lp;
}

// Hot-loop lgamma: branchless 2-term Stirling (|err|<0.01 for x>=0.5).
__device__ __forceinline__ float stirling_lg(float x) {
    float inv  = fast_rcp(x);
    float inv2 = inv * inv;
    float ser  = inv * (0.08333333333f - 0.002777777778f * inv2);
    return (x - 0.5f) * __logf(x) - x + 0.9189385332f + ser;
}

__device__ __forceinline__ float softplus_f(float x) {
    return fmaxf(x, 0.0f) + log1pf(__expf(-fabsf(x)));
}

__device__ __forceinline__ float wave_reduce(float v) {
#pragma unroll
    for (int off = 32; off; off >>= 1) v += __shfl_down(v, off, 64);
    return v;
}

// one NB element:  lgamma(y+r)-lgamma(y+1) + y*lm - (y+r)*log(r+m) + cg
__device__ __forceinline__ float nbterm(float y, float lm, float r, float cgv) {
    float m  = __expf(lm);
    float yr = y + r;
    return stirling_lg(yr) - stirling_lg(y + 1.0f)
         + fmaf(y, lm, -yr * __logf(r + m)) + cgv;
}

// ---------------------------------------------------------------------------
// Fused cooperative kernel (N=1024, G=20000, P=4 only).
// ---------------------------------------------------------------------------
__global__ __launch_bounds__(256, 3) void fused_kernel(
        const float* __restrict__ X, const float* __restrict__ Y,
        const float* __restrict__ mu, const float* __restrict__ beta,
        const float* __restrict__ phi,
        float* __restrict__ syw, float* __restrict__ sew,
        float* __restrict__ rgw, float* __restrict__ cgw,
        double* __restrict__ acc, float* __restrict__ out) {
    __shared__ unsigned short ycache[3 * FN_SR * 1000];  // 48 KB
    __shared__ float xsh[FN_K * FN_SR * 4];              // 512 B
    __shared__ float dcs[FN_K * FN_SR];                  // 128 B
    __shared__ float red[4];

    const int tid = threadIdx.x;
    const int b   = blockIdx.x;
    const int c   = b % FN_C;
    const int s0  = b / FN_C;                 // [0,32)
    const bool active = (tid < FN_CW4);
    const int gi4 = c * FN_CW4 + (active ? tid : 0);
    const int lane = tid & 63;
    const float4 zero = make_float4(0, 0, 0, 0);

    // stage X for this block's 4 slabs (32 rows x 4 preds)
    if (tid < FN_K * FN_SR * 4) {
        int k = tid >> 5, i = tid & 31;
        xsh[tid] = X[(size_t)(8 * s0 + 256 * k) * 4 + i];
    }

    const float4* __restrict__ Y4 = (const float4*)Y;
    float4 bb[4], mug;
    if (active) {
        const float4* __restrict__ B4 = (const float4*)beta;
#pragma unroll
        for (int p = 0; p < 4; ++p) bb[p] = B4[(size_t)p * FN_G4 + gi4];
        mug = ((const float4*)mu)[gi4];
    } else {
        mug = zero;
#pragma unroll
        for (int p = 0; p < 4; ++p) bb[p] = zero;
    }

    // priors + r,cg tables: one block per gene chunk
    float priorv = 0.0f;
    if (b < FN_C && active) {
        const float cn = -1.6120857137646180f;  // -0.5*log(8*pi)
        float4 ph = ((const float4*)phi)[gi4];
        float4 r4p, cg4p;
        float mm = mug.x; priorv += cn - mm * mm * 0.125f;
        mm = mug.y; priorv += cn - mm * mm * 0.125f;
        mm = mug.z; priorv += cn - mm * mm * 0.125f;
        mm = mug.w; priorv += cn - mm * mm * 0.125f;
#pragma unroll
        for (int p = 0; p < 4; ++p) {
            priorv += cn - bb[p].x * bb[p].x * 0.125f;
            priorv += cn - bb[p].y * bb[p].y * 0.125f;
            priorv += cn - bb[p].z * bb[p].z * 0.125f;
            priorv += cn - bb[p].w * bb[p].w * 0.125f;
        }
        float sp;
        sp = softplus_f(ph.x); priorv += __logf(sp) - sp; r4p.x = 1.0f / sp;
        cg4p.x = r4p.x * __logf(r4p.x) - lgamma_pos(r4p.x);
        sp = softplus_f(ph.y); priorv += __logf(sp) - sp; r4p.y = 1.0f / sp;
        cg4p.y = r4p.y * __logf(r4p.y) - lgamma_pos(r4p.y);
        sp = softplus_f(ph.z); priorv += __logf(sp) - sp; r4p.z = 1.0f / sp;
        cg4p.z = r4p.z * __logf(r4p.z) - lgamma_pos(r4p.z);
        sp = softplus_f(ph.w); priorv += __logf(sp) - sp; r4p.w = 1.0f / sp;
        cg4p.w = r4p.w * __logf(r4p.w) - lgamma_pos(r4p.w);
        ((float4*)rgw)[gi4] = r4p;
        ((float4*)cgw)[gi4] = cg4p;
    }
    __syncthreads();   // xsh ready

    // ---- phase 1: stream Y, build sy/se, cache tiles 0..2 as ushort ----
    auto load_tile = [&](int k, float4 (&dst)[8]) {
#pragma unroll
        for (int r = 0; r < 8; ++r)
            dst[r] = active ? Y4[(size_t)(8 * s0 + 256 * k + r) * FN_G4 + gi4] : zero;
    };
    auto proc_tile = [&](int k, float4 (&src)[8]) {
        float syr[8], ser[8];
#pragma unroll
        for (int r = 0; r < 8; ++r) {
            float4 y = src[r];
            if (k < 3 && active) {
                *(ushort4*)&ycache[k * 8000 + r * 1000 + 4 * tid] =
                    make_ushort4((unsigned short)__float2uint_rz(y.x),
                                 (unsigned short)__float2uint_rz(y.y),
                                 (unsigned short)__float2uint_rz(y.z),
                                 (unsigned short)__float2uint_rz(y.w));
            }
            syr[r] = (y.x + y.y) + (y.z + y.w);
            float4 lu = mug;
#pragma unroll
            for (int p = 0; p < 4; ++p) {
                float xp = xsh[k * 32 + r * 4 + p];
                lu.x = fmaf(xp, bb[p].x, lu.x);
                lu.y = fmaf(xp, bb[p].y, lu.y);
                lu.z = fmaf(xp, bb[p].z, lu.z);
                lu.w = fmaf(xp, bb[p].w, lu.w);
            }
            float e = (__expf(lu.x) + __expf(lu.y)) + (__expf(lu.z) + __expf(lu.w));
            ser[r] = active ? e : 0.0f;
        }
        // 16 interleaved shuffle-reduce chains (batched, pipelined)
#pragma unroll
        for (int off = 32; off; off >>= 1) {
#pragma unroll
            for (int r = 0; r < 8; ++r) {
                syr[r] += __shfl_down(syr[r], off, 64);
                ser[r] += __shfl_down(ser[r], off, 64);
            }
        }
        if (lane == 0) {
            int n0k = 8 * s0 + 256 * k;
#pragma unroll
            for (int r = 0; r < 8; ++r) {
                atomicAdd(&syw[n0k + r], syr[r]);
                atomicAdd(&sew[n0k + r], ser[r]);
            }
        }
    };

    float4 buf0[8], buf1[8];
    load_tile(0, buf0);
    load_tile(1, buf1);
    proc_tile(0, buf0);
    load_tile(2, buf0);
    proc_tile(1, buf1);
    load_tile(3, buf1);
    proc_tile(2, buf0);
    proc_tile(3, buf1);

    __threadfence();
    cgrp::this_grid().sync();

    // ---- phase 2: likelihood ----
    if (tid < FN_K * FN_SR) {
        int k = tid >> 3, r = tid & 7;
        int n = 8 * s0 + 256 * k + r;
        dcs[tid] = __logf(syw[n]) - __logf(sew[n]);
    }
    float4 r4, cg4;
    if (active) {
        r4  = ((const float4*)rgw)[gi4];
        cg4 = ((const float4*)cgw)[gi4];
    } else {
        r4 = make_float4(1, 1, 1, 1); cg4 = zero;
    }
    // issue the uncached tile's global reads first (latency hidden by LDS work)
    float4 g3[8];
#pragma unroll
    for (int r = 0; r < 8; ++r)
        g3[r] = active ? Y4[(size_t)(8 * s0 + 768 + r) * FN_G4 + gi4] : zero;
    __syncthreads();   // dcs ready

    float a0 = 0.0f, a1 = 0.0f, a2 = 0.0f, a3 = 0.0f;
    auto elem = [&](int k, int r, float4 y) {
        float dcn = dcs[k * 8 + r];
        float4 lu = mug;
#pragma unroll
        for (int p = 0; p < 4; ++p) {
            float xp = xsh[k * 32 + r * 4 + p];
            lu.x = fmaf(xp, bb[p].x, lu.x);
            lu.y = fmaf(xp, bb[p].y, lu.y);
            lu.z = fmaf(xp, bb[p].z, lu.z);
            lu.w = fmaf(xp, bb[p].w, lu.w);
        }
        a0 += nbterm(y.x, dcn + lu.x, r4.x, cg4.x);
        a1 += nbterm(y.y, dcn + lu.y, r4.y, cg4.y);
        a2 += nbterm(y.z, dcn + lu.z, r4.z, cg4.z);
        a3 += nbterm(y.w, dcn + lu.w, r4.w, cg4.w);
    };
#pragma unroll
    for (int k = 0; k < 3; ++k) {
#pragma unroll
        for (int r = 0; r < 8; ++r) {
            ushort4 u = *(const ushort4*)&ycache[k * 8000 + r * 1000 + 4 * (active ? tid : 0)];
            float4 y = make_float4((float)u.x, (float)u.y, (float)u.z, (float)u.w);
            elem(k, r, y);
        }
    }
#pragma unroll
    for (int r = 0; r < 8; ++r) elem(3, r, g3[r]);

    float accl = (active ? ((a0 + a1) + (a2 + a3)) : 0.0f) + priorv;
    accl = wave_reduce(accl);
    int wid = tid >> 6;
    if (lane == 0) red[wid] = accl;
    __syncthreads();
    if (tid == 0)
        atomicAdd(acc, (double)((red[0] + red[1]) + (red[2] + red[3])));

    cgrp::this_grid().sync();
    if (b == 0 && tid == 0)
        out[0] = (float)atomicAdd(acc, 0.0);
}

// ---------------------------------------------------------------------------
// Generic fallback path (any shape, or cooperative launch unsupported).
// ---------------------------------------------------------------------------
__global__ __launch_bounds__(256) void setup_kernel(
        const float* __restrict__ mu, const float* __restrict__ beta,
        const float* __restrict__ phi, double* __restrict__ acc,
        float* __restrict__ rg, float* __restrict__ cgw, int P, int G) {
    int g = blockIdx.x * 256 + threadIdx.x;
    float v = 0.0f;
    if (g < G) {
        const float cn = -1.6120857137646180f;
        float m = mu[g];
        v = cn - m * m * 0.125f;
        for (int p = 0; p < P; ++p) {
            float bv = beta[(size_t)p * G + g];
            v += cn - bv * bv * 0.125f;
        }
        float sp = softplus_f(phi[g]);
        v += __logf(sp) - sp;
        float r = 1.0f / sp;
        rg[g]  = r;
        cgw[g] = r * __logf(r) - lgamma_pos(r);
    }
    v = wave_reduce(v);
    __shared__ float red[4];
    int lane = threadIdx.x & 63, wid = threadIdx.x >> 6;
    if (lane == 0) red[wid] = v;
    __syncthreads();
    if (threadIdx.x == 0)
        atomicAdd(acc, (double)((red[0] + red[1]) + (red[2] + red[3])));
}

__global__ void row_stats_generic(
        const float* __restrict__ X, const float* __restrict__ Y,
        const float* __restrict__ mu, const float* __restrict__ beta,
        float* __restrict__ syw, float* __restrict__ sew, int N, int P, int G) {
    const int n = blockIdx.x;
    const int tid = threadIdx.x;
    float sy = 0.0f, se = 0.0f;
    for (int g = tid; g < G; g += 256) {
        sy += Y[(size_t)n * G + g];
        float lu = mu[g];
        for (int p = 0; p < P; ++p) lu += X[(size_t)n * P + p] * beta[(size_t)p * G + g];
        se += __expf(lu);
    }
    sy = wave_reduce(sy);
    se = wave_reduce(se);
    __shared__ float r1[4], r2[4];
    int lane = tid & 63, wid = tid >> 6;
    if (lane == 0) { r1[wid] = sy; r2[wid] = se; }
    __syncthreads();
    if (tid == 0) {
        syw[n] = (r1[0] + r1[1]) + (r1[2] + r1[3]);
        sew[n] = (r2[0] + r2[1]) + (r2[2] + r2[3]);
    }
}

__global__ void nb_generic(
        const float* __restrict__ X, const float* __restrict__ Y,
        const float* __restrict__ mu, const float* __restrict__ beta,
        const float* __restrict__ rg, const float* __restrict__ cgw,
        const float* __restrict__ syw, const float* __restrict__ sew,
        double* __restrict__ acc, int N, int P, int G) {
    const int n = blockIdx.x;
    const int tid = threadIdx.x;
    float dcn = __logf(syw[n]) - __logf(sew[n]);
    float accl = 0.0f;
    for (int g = tid; g < G; g += 256) {
        float y = Y[(size_t)n * G + g];
        float lu = mu[g];
        for (int p = 0; p < P; ++p) lu += X[(size_t)n * P + p] * beta[(size_t)p * G + g];
        float lm = dcn + lu;
        float r = rg[g];
        float m = __expf(lm);
        accl += stirling_lg(y + r) - lgamma_pos(y + 1.0f)
                + fmaf(y, lm, -(y + r) * __logf(r + m)) + cgw[g];
    }
    accl = wave_reduce(accl);
    __shared__ float red[4];
    int lane = tid & 63, wid = tid >> 6;
    if (lane == 0) red[wid] = accl;
    __syncthreads();
    if (tid == 0)
        atomicAdd(acc, (double)((red[0] + red[1]) + (red[2] + red[3])));
}

__global__ void finalize_kernel(const double* __restrict__ acc, float* __restrict__ out) {
    out[0] = (float)acc[0];
}

// ---------------------------------------------------------------------------
extern "C" void kernel_launch(void* const* d_in, const int* in_sizes, int n_in,
                              void* d_out, int out_size, void* d_ws, size_t ws_size,
                              hipStream_t stream) {
    const float* X    = (const float*)d_in[0];
    const float* Y    = (const float*)d_in[1];
    const float* mu   = (const float*)d_in[2];
    const float* beta = (const float*)d_in[3];
    const float* phi  = (const float*)d_in[4];
    float* out = (float*)d_out;

    const int G = in_sizes[2];
    const int N = in_sizes[1] / G;
    const int P = in_sizes[0] / N;

    // ws layout: acc@0 (8B) | syw@256 [N] | sew@4608 [N] | rg@8960 [G] | cg [G]
    char* ws = (char*)d_ws;
    double* acc = (double*)ws;
    float*  syw = (float*)(ws + 256);
    float*  sew = (float*)(ws + 4608);
    float*  rgw = (float*)(ws + 8960);
    float*  cgw = (float*)(ws + 8960 + (size_t)4 * G);

    hipMemsetAsync(d_ws, 0, 8960, stream);   // acc + syw + sew

    bool fast_ok = (N == FN_N && G == FN_G && P == 4);
    if (fast_ok) {
        void* args[] = {(void*)&X, (void*)&Y, (void*)&mu, (void*)&beta, (void*)&phi,
                        (void*)&syw, (void*)&sew, (void*)&rgw, (void*)&cgw,
                        (void*)&acc, (void*)&out};
        hipError_t e = hipLaunchCooperativeKernel((const void*)fused_kernel,
                                                  dim3(FN_B), dim3(256),
                                                  args, 0, stream);
        if (e == hipSuccess) return;
        fast_ok = false;  // fall through to generic path
    }
    {
        int gblocks = (G + 255) / 256;
        setup_kernel<<<gblocks, 256, 0, stream>>>(mu, beta, phi, acc, rgw, cgw, P, G);
        row_stats_generic<<<N, 256, 0, stream>>>(X, Y, mu, beta, syw, sew, N, P, G);
        nb_generic<<<N, 256, 0, stream>>>(X, Y, mu, beta, rgw, cgw, syw, sew,
                                          acc, N, P, G);
        finalize_kernel<<<1, 1, 0, stream>>>(acc, out);
    }
}

// Round 7
// 202.691 us; speedup vs baseline: 1.9974x; 1.9974x over previous
//
#include <hip/hip_runtime.h>
#include <math.h>

// ---------------------------------------------------------------------------
// NB regression log-posterior, two-pass, grid-stride work-item design.
//   setup:  priors + per-gene r, cg = r*log r - lgamma(r)
//   pre:    sy[n] = sum_g Y;  se[n] = sum_g exp(mu+X.beta);
//           ALSO packs Y into ws as ushort (exact: y in [0,500)).
//   K2:     sum_{n,g} [ st(y+r) - st(y+1) + y*lm - (y+r)*log(r+m) + cg ],
//           lm = dc[n]+mu+X.beta, dc = log sy - log se, m = exp(lm),
//           reading the 41 MB packed copy (half the bytes of Y).
//   finalize: out = (float)acc
// Work decomposition (fast path N=1024,G=20000,P=4): 20 gene-chunks x 64
// row-slabs = 1280 items, grid-stride over 640 blocks (2 items/block) --
// tests the per-workgroup-overhead theory from R1-R5's flat ~58us/pass.
// Tolerance: 2% of ~2.3e9 -> fast transcendentals + 2-term Stirling safe.
// ---------------------------------------------------------------------------

#define FG4    5000    // float4s per gene row (G/4)
#define FCH    20      // gene chunks of 256 float4s (ceil(5000/256))
#define FSLABS 64      // row slabs of 16 (N/16)
#define FITEMS (FCH * FSLABS)
#define FGRID  640     // 2 items per block

__device__ __forceinline__ float fast_rcp(float x) {
    return __builtin_amdgcn_rcpf(x);
}

// Accurate lgamma (setup / generic fallback only).
__device__ __forceinline__ float lgamma_pos(float x) {
    float lp = 0.0f;
    if (x < 8.0f) {
        float p = x;
        x += 1.0f;
        while (x < 8.0f) { p *= x; x += 1.0f; }
        lp = __logf(p);
    }
    float inv  = fast_rcp(x);
    float inv2 = inv * inv;
    float ser = inv * (0.08333333333f + inv2 * (-0.002777777778f + inv2 * 7.936507937e-4f));
    return (x - 0.5f) * __logf(x) - x + 0.9189385332f + ser - lp;
}

// Hot-loop lgamma: branchless 2-term Stirling (|err|<1e-3 for x>=1).
__device__ __forceinline__ float stirling_lg(float x) {
    float inv  = fast_rcp(x);
    float inv2 = inv * inv;
    float ser  = inv * (0.08333333333f - 0.002777777778f * inv2);
    return (x - 0.5f) * __logf(x) - x + 0.9189385332f + ser;
}

__device__ __forceinline__ float softplus_f(float x) {
    return fmaxf(x, 0.0f) + log1pf(__expf(-fabsf(x)));
}

__device__ __forceinline__ float wave_reduce(float v) {
#pragma unroll
    for (int off = 32; off; off >>= 1) v += __shfl_down(v, off, 64);
    return v;
}

// lgamma(y+r) - lgamma(y+1) + y*lm - (y+r)*log(r+m) + cg
__device__ __forceinline__ float nbterm(float y, float lm, float r, float cgv) {
    float m  = __expf(lm);
    float yr = y + r;
    return stirling_lg(yr) - stirling_lg(y + 1.0f)
         + fmaf(y, lm, -yr * __logf(r + m)) + cgv;
}

// ---------------------------------------------------------------------------
// K0 setup: priors + per-gene r[g], cg[g].
// ---------------------------------------------------------------------------
__global__ __launch_bounds__(256) void setup_kernel(
        const float* __restrict__ mu, const float* __restrict__ beta,
        const float* __restrict__ phi, double* __restrict__ acc,
        float* __restrict__ rg, float* __restrict__ cgw, int P, int G) {
    int g = blockIdx.x * 256 + threadIdx.x;
    float v = 0.0f;
    if (g < G) {
        const float cn = -1.6120857137646180f;  // -0.5*log(8*pi)
        float m = mu[g];
        v = cn - m * m * 0.125f;
        for (int p = 0; p < P; ++p) {
            float b = beta[(size_t)p * G + g];
            v += cn - b * b * 0.125f;
        }
        float sp = softplus_f(phi[g]);
        v += __logf(sp) - sp;
        float r = 1.0f / sp;
        rg[g]  = r;
        cgw[g] = r * __logf(r) - lgamma_pos(r);
    }
    v = wave_reduce(v);
    __shared__ float red[4];
    int lane = threadIdx.x & 63, wid = threadIdx.x >> 6;
    if (lane == 0) red[wid] = v;
    __syncthreads();
    if (threadIdx.x == 0)
        atomicAdd(acc, (double)((red[0] + red[1]) + (red[2] + red[3])));
}

// ---------------------------------------------------------------------------
// K1 pre: sy/se per row + pack Y into ushort. Grid-stride over 1280 items.
// ---------------------------------------------------------------------------
__global__ __launch_bounds__(256) void pre_fast(
        const float* __restrict__ X, const float* __restrict__ Y,
        const float* __restrict__ mu, const float* __restrict__ beta,
        float* __restrict__ syw, float* __restrict__ sew,
        unsigned short* __restrict__ ypack) {
    __shared__ float Xs[64];
    __shared__ float syp[4][16], sep[4][16];

    const int tid  = threadIdx.x;
    const int lane = tid & 63, wid = tid >> 6;
    const float4* __restrict__ Y4 = (const float4*)Y;
    const float4* __restrict__ B4 = (const float4*)beta;
    const float4* __restrict__ M4 = (const float4*)mu;
    const float4 zero = make_float4(0, 0, 0, 0);

    for (int w = blockIdx.x; w < FITEMS; w += gridDim.x) {
        const int c  = w % FCH;
        const int s  = w / FCH;
        const int n0 = s * 16;
        __syncthreads();                       // protect LDS from prev item
        if (tid < 64) Xs[tid] = X[(size_t)n0 * 4 + tid];
        const int gi4 = c * 256 + tid;
        const bool active = (gi4 < FG4);
        float4 bb[4], mug;
        if (active) {
#pragma unroll
            for (int p = 0; p < 4; ++p) bb[p] = B4[(size_t)p * FG4 + gi4];
            mug = M4[gi4];
        } else {
            mug = zero;
#pragma unroll
            for (int p = 0; p < 4; ++p) bb[p] = zero;
        }
        __syncthreads();                       // Xs ready

        const float4* __restrict__ Yp = Y4 + (size_t)n0 * FG4 + (active ? gi4 : 0);
        ushort4* __restrict__ Wp = (ushort4*)ypack + (size_t)n0 * FG4 + (active ? gi4 : 0);

#pragma unroll
        for (int i0 = 0; i0 < 16; i0 += 4) {
            float4 y[4];
#pragma unroll
            for (int j = 0; j < 4; ++j)
                y[j] = active ? Yp[(size_t)(i0 + j) * FG4] : zero;
            float sy[4], se[4];
#pragma unroll
            for (int j = 0; j < 4; ++j) {
                if (active) {
                    Wp[(size_t)(i0 + j) * FG4] =
                        make_ushort4((unsigned short)__float2uint_rz(y[j].x),
                                     (unsigned short)__float2uint_rz(y[j].y),
                                     (unsigned short)__float2uint_rz(y[j].z),
                                     (unsigned short)__float2uint_rz(y[j].w));
                }
                float4 lu = mug;
#pragma unroll
                for (int p = 0; p < 4; ++p) {
                    float xp = Xs[(i0 + j) * 4 + p];
                    lu.x = fmaf(xp, bb[p].x, lu.x);
                    lu.y = fmaf(xp, bb[p].y, lu.y);
                    lu.z = fmaf(xp, bb[p].z, lu.z);
                    lu.w = fmaf(xp, bb[p].w, lu.w);
                }
                float e = (__expf(lu.x) + __expf(lu.y)) + (__expf(lu.z) + __expf(lu.w));
                se[j] = active ? e : 0.0f;
                sy[j] = (y[j].x + y[j].y) + (y[j].z + y[j].w);
            }
#pragma unroll
            for (int off = 32; off; off >>= 1) {
#pragma unroll
                for (int j = 0; j < 4; ++j) {
                    sy[j] += __shfl_down(sy[j], off, 64);
                    se[j] += __shfl_down(se[j], off, 64);
                }
            }
            if (lane == 0) {
#pragma unroll
                for (int j = 0; j < 4; ++j) {
                    syp[wid][i0 + j] = sy[j];
                    sep[wid][i0 + j] = se[j];
                }
            }
        }
        __syncthreads();
        if (tid < 16) {
            float a = (syp[0][tid] + syp[1][tid]) + (syp[2][tid] + syp[3][tid]);
            float b = (sep[0][tid] + sep[1][tid]) + (sep[2][tid] + sep[3][tid]);
            atomicAdd(&syw[n0 + tid], a);
            atomicAdd(&sew[n0 + tid], b);
        }
    }
}

// ---------------------------------------------------------------------------
// K2: likelihood from packed Y (41 MB). Grid-stride over 1280 items;
// one double-atomic per block at the very end.
// ---------------------------------------------------------------------------
__global__ __launch_bounds__(256) void nb_fast(
        const float* __restrict__ X,
        const float* __restrict__ mu, const float* __restrict__ beta,
        const float* __restrict__ rg, const float* __restrict__ cgw,
        const float* __restrict__ syw, const float* __restrict__ sew,
        const unsigned short* __restrict__ ypack,
        double* __restrict__ acc) {
    __shared__ float Xs[64];
    __shared__ float dcs[16];
    __shared__ float red[4];

    const int tid  = threadIdx.x;
    const int lane = tid & 63, wid = tid >> 6;
    const float4* __restrict__ B4 = (const float4*)beta;
    const float4 zero = make_float4(0, 0, 0, 0);

    float a0 = 0.0f, a1 = 0.0f, a2 = 0.0f, a3 = 0.0f;

    for (int w = blockIdx.x; w < FITEMS; w += gridDim.x) {
        const int c  = w % FCH;
        const int s  = w / FCH;
        const int n0 = s * 16;
        __syncthreads();
        if (tid < 64) Xs[tid] = X[(size_t)n0 * 4 + tid];
        if (tid < 16) dcs[tid] = __logf(syw[n0 + tid]) - __logf(sew[n0 + tid]);
        const int gi4 = c * 256 + tid;
        const bool active = (gi4 < FG4);
        float4 bb[4], mug, r4, cg4;
        if (active) {
#pragma unroll
            for (int p = 0; p < 4; ++p) bb[p] = B4[(size_t)p * FG4 + gi4];
            mug = ((const float4*)mu)[gi4];
            r4  = ((const float4*)rg)[gi4];
            cg4 = ((const float4*)cgw)[gi4];
        } else {
            mug = zero; cg4 = zero; r4 = make_float4(1, 1, 1, 1);
#pragma unroll
            for (int p = 0; p < 4; ++p) bb[p] = zero;
        }
        __syncthreads();                       // Xs, dcs ready

        const ushort4* __restrict__ Yp =
            (const ushort4*)ypack + (size_t)n0 * FG4 + (active ? gi4 : 0);
        ushort4 yb[4];
#pragma unroll
        for (int j = 0; j < 4; ++j) yb[j] = Yp[(size_t)j * FG4];

        float t0 = 0.0f, t1 = 0.0f, t2 = 0.0f, t3 = 0.0f;
#pragma unroll
        for (int i = 0; i < 16; ++i) {
            ushort4 u = yb[i & 3];
            if (i + 4 < 16) yb[i & 3] = Yp[(size_t)(i + 4) * FG4];
            float4 y = make_float4((float)u.x, (float)u.y, (float)u.z, (float)u.w);
            float dcn = dcs[i];
            float4 lu = mug;
#pragma unroll
            for (int p = 0; p < 4; ++p) {
                float xp = Xs[i * 4 + p];
                lu.x = fmaf(xp, bb[p].x, lu.x);
                lu.y = fmaf(xp, bb[p].y, lu.y);
                lu.z = fmaf(xp, bb[p].z, lu.z);
                lu.w = fmaf(xp, bb[p].w, lu.w);
            }
            t0 += nbterm(y.x, dcn + lu.x, r4.x, cg4.x);
            t1 += nbterm(y.y, dcn + lu.y, r4.y, cg4.y);
            t2 += nbterm(y.z, dcn + lu.z, r4.z, cg4.z);
            t3 += nbterm(y.w, dcn + lu.w, r4.w, cg4.w);
        }
        if (active) { a0 += t0; a1 += t1; a2 += t2; a3 += t3; }
    }

    float accl = (a0 + a1) + (a2 + a3);
    accl = wave_reduce(accl);
    if (lane == 0) red[wid] = accl;
    __syncthreads();
    if (tid == 0)
        atomicAdd(acc, (double)((red[0] + red[1]) + (red[2] + red[3])));
}

__global__ void finalize_kernel(const double* __restrict__ acc, float* __restrict__ out) {
    out[0] = (float)acc[0];
}

// ---------------------------------------------------------------------------
// Generic fallbacks (correctness only).
// ---------------------------------------------------------------------------
__global__ void row_stats_generic(
        const float* __restrict__ X, const float* __restrict__ Y,
        const float* __restrict__ mu, const float* __restrict__ beta,
        float* __restrict__ syw, float* __restrict__ sew, int N, int P, int G) {
    const int n = blockIdx.x;
    const int tid = threadIdx.x;
    float sy = 0.0f, se = 0.0f;
    for (int g = tid; g < G; g += 256) {
        sy += Y[(size_t)n * G + g];
        float lu = mu[g];
        for (int p = 0; p < P; ++p) lu += X[(size_t)n * P + p] * beta[(size_t)p * G + g];
        se += __expf(lu);
    }
    sy = wave_reduce(sy);
    se = wave_reduce(se);
    __shared__ float r1[4], r2[4];
    int lane = tid & 63, wid = tid >> 6;
    if (lane == 0) { r1[wid] = sy; r2[wid] = se; }
    __syncthreads();
    if (tid == 0) {
        syw[n] = (r1[0] + r1[1]) + (r1[2] + r1[3]);
        sew[n] = (r2[0] + r2[1]) + (r2[2] + r2[3]);
    }
}

__global__ void nb_generic(
        const float* __restrict__ X, const float* __restrict__ Y,
        const float* __restrict__ mu, const float* __restrict__ beta,
        const float* __restrict__ rg, const float* __restrict__ cgw,
        const float* __restrict__ syw, const float* __restrict__ sew,
        double* __restrict__ acc, int N, int P, int G) {
    const int n = blockIdx.x;
    const int tid = threadIdx.x;
    float dcn = __logf(syw[n]) - __logf(sew[n]);
    float accl = 0.0f;
    for (int g = tid; g < G; g += 256) {
        float y = Y[(size_t)n * G + g];
        float lu = mu[g];
        for (int p = 0; p < P; ++p) lu += X[(size_t)n * P + p] * beta[(size_t)p * G + g];
        float lm = dcn + lu;
        float r = rg[g];
        float m = __expf(lm);
        accl += stirling_lg(y + r) - lgamma_pos(y + 1.0f)
                + fmaf(y, lm, -(y + r) * __logf(r + m)) + cgw[g];
    }
    accl = wave_reduce(accl);
    __shared__ float red[4];
    int lane = tid & 63, wid = tid >> 6;
    if (lane == 0) red[wid] = accl;
    __syncthreads();
    if (tid == 0)
        atomicAdd(acc, (double)((red[0] + red[1]) + (red[2] + red[3])));
}

// ---------------------------------------------------------------------------
extern "C" void kernel_launch(void* const* d_in, const int* in_sizes, int n_in,
                              void* d_out, int out_size, void* d_ws, size_t ws_size,
                              hipStream_t stream) {
    const float* X    = (const float*)d_in[0];
    const float* Y    = (const float*)d_in[1];
    const float* mu   = (const float*)d_in[2];
    const float* beta = (const float*)d_in[3];
    const float* phi  = (const float*)d_in[4];
    float* out = (float*)d_out;

    const int G = in_sizes[2];
    const int N = in_sizes[1] / G;
    const int P = in_sizes[0] / N;

    // ws layout: acc@0 | syw@256 [N] | sew@4608 [N] | rg@8960 [G] |
    //            cg@8960+4G [G] | ypack@262144 [N*G ushort]
    char* ws = (char*)d_ws;
    double*         acc   = (double*)ws;
    float*          syw   = (float*)(ws + 256);
    float*          sew   = (float*)(ws + 4608);
    float*          rgw   = (float*)(ws + 8960);
    float*          cgw   = (float*)(ws + 8960 + (size_t)4 * G);
    unsigned short* ypack = (unsigned short*)(ws + 262144);

    hipMemsetAsync(d_ws, 0, 8960, stream);   // acc + syw + sew

    const size_t need = 262144 + (size_t)2 * N * G;
    const bool fast_ok = (N == 1024 && G == 20000 && P == 4 && ws_size >= need);

    int gblocks = (G + 255) / 256;
    if (fast_ok) {
        pre_fast<<<FGRID, 256, 0, stream>>>(X, Y, mu, beta, syw, sew, ypack);
        setup_kernel<<<gblocks, 256, 0, stream>>>(mu, beta, phi, acc, rgw, cgw, P, G);
        nb_fast<<<FGRID, 256, 0, stream>>>(X, mu, beta, rgw, cgw, syw, sew, ypack, acc);
    } else {
        setup_kernel<<<gblocks, 256, 0, stream>>>(mu, beta, phi, acc, rgw, cgw, P, G);
        row_stats_generic<<<N, 256, 0, stream>>>(X, Y, mu, beta, syw, sew, N, P, G);
        nb_generic<<<N, 256, 0, stream>>>(X, Y, mu, beta, rgw, cgw, syw, sew,
                                          acc, N, P, G);
    }
    finalize_kernel<<<1, 1, 0, stream>>>(acc, out);
}

// Round 8
// 167.284 us; speedup vs baseline: 2.4202x; 1.2117x over previous
//
#include <hip/hip_runtime.h>
#include <math.h>

// ---------------------------------------------------------------------------
// NB regression log-posterior, two-pass.
//   setup:  priors + per-gene r, cg = r*log r - lgamma(r)
//   pre:    sy[n] = sum_g Y;  se[n] = sum_g exp(mu+X.beta)
//   K2:     sum_{n,g} [ st(y+r) - lgY[y] + y*lm - (y+r)*log(r+m) + cg ],
//           lm = dc[n]+mu+X.beta, dc = log sy - log se, m = exp(lm)
//   finalize: out = (float)acc
// Fast path (N=1024,G=20000,P=4): 20 gene-chunks x 250 float4 x 64 row-slabs
// = 1280 blocks, one item per block. Deep load batching (8-16 independent
// dwordx4 in flight) per R7's finding that bytes don't matter but request
// concurrency might. LDS lgamma(y+1) table cuts ~25% of hot-loop VALU.
// Tolerance: 2% of ~2.3e9 -> fast transcendentals + 2-term Stirling safe.
// ---------------------------------------------------------------------------

#define FG4   5000    // float4s per gene row (G/4)
#define FCH4  250     // float4s per chunk (1000 genes)
#define FNCH  20      // gene chunks
#define FNSL  64      // row slabs of 16
#define FNBLK 1280    // FNCH * FNSL

__device__ __forceinline__ float fast_rcp(float x) {
    return __builtin_amdgcn_rcpf(x);
}

// Accurate lgamma (table build / setup / generic fallback).
__device__ __forceinline__ float lgamma_pos(float x) {
    float lp = 0.0f;
    if (x < 8.0f) {
        float p = x;
        x += 1.0f;
        while (x < 8.0f) { p *= x; x += 1.0f; }
        lp = __logf(p);
    }
    float inv  = fast_rcp(x);
    float inv2 = inv * inv;
    float ser = inv * (0.08333333333f + inv2 * (-0.002777777778f + inv2 * 7.936507937e-4f));
    return (x - 0.5f) * __logf(x) - x + 0.9189385332f + ser - lp;
}

// Hot-loop lgamma for y+r (>= r ~ 1.4 typ): branchless 2-term Stirling.
__device__ __forceinline__ float stirling_lg(float x) {
    float inv  = fast_rcp(x);
    float inv2 = inv * inv;
    float ser  = inv * (0.08333333333f - 0.002777777778f * inv2);
    return (x - 0.5f) * __logf(x) - x + 0.9189385332f + ser;
}

__device__ __forceinline__ float softplus_f(float x) {
    return fmaxf(x, 0.0f) + log1pf(__expf(-fabsf(x)));
}

__device__ __forceinline__ float wave_reduce(float v) {
#pragma unroll
    for (int off = 32; off; off >>= 1) v += __shfl_down(v, off, 64);
    return v;
}

// ---------------------------------------------------------------------------
// K0 setup: priors + per-gene r[g], cg[g].
// ---------------------------------------------------------------------------
__global__ __launch_bounds__(256) void setup_kernel(
        const float* __restrict__ mu, const float* __restrict__ beta,
        const float* __restrict__ phi, double* __restrict__ acc,
        float* __restrict__ rg, float* __restrict__ cgw, int P, int G) {
    int g = blockIdx.x * 256 + threadIdx.x;
    float v = 0.0f;
    if (g < G) {
        const float cn = -1.6120857137646180f;  // -0.5*log(8*pi)
        float m = mu[g];
        v = cn - m * m * 0.125f;
        for (int p = 0; p < P; ++p) {
            float b = beta[(size_t)p * G + g];
            v += cn - b * b * 0.125f;
        }
        float sp = softplus_f(phi[g]);
        v += __logf(sp) - sp;
        float r = 1.0f / sp;
        rg[g]  = r;
        cgw[g] = r * __logf(r) - lgamma_pos(r);
    }
    v = wave_reduce(v);
    __shared__ float red[4];
    int lane = threadIdx.x & 63, wid = threadIdx.x >> 6;
    if (lane == 0) red[wid] = v;
    __syncthreads();
    if (threadIdx.x == 0)
        atomicAdd(acc, (double)((red[0] + red[1]) + (red[2] + red[3])));
}

// ---------------------------------------------------------------------------
// K1 pre: sy/se per row. 1280 blocks, 16 float4 rows in flight.
// ---------------------------------------------------------------------------
__global__ __launch_bounds__(256, 4) void pre_fast(
        const float* __restrict__ X, const float* __restrict__ Y,
        const float* __restrict__ mu, const float* __restrict__ beta,
        float* __restrict__ syw, float* __restrict__ sew) {
    __shared__ float Xs[64];
    __shared__ float syp[4][16], sep[4][16];

    const int tid  = threadIdx.x;
    const int lane = tid & 63, wid = tid >> 6;
    const int c    = blockIdx.x % FNCH;
    const int s    = blockIdx.x / FNCH;
    const int n0   = s * 16;
    const bool active = (tid < FCH4);
    const int gi4  = c * FCH4 + (active ? tid : FCH4 - 1);

    // issue all 16 Y row loads first (deep MLP)
    const float4* __restrict__ Yp = (const float4*)Y + (size_t)n0 * FG4 + gi4;
    float4 ya[16];
#pragma unroll
    for (int j = 0; j < 16; ++j) ya[j] = Yp[(size_t)j * FG4];

    // stage X while loads fly
    if (tid < 64) Xs[tid] = X[(size_t)n0 * 4 + tid];
    const float4* __restrict__ B4 = (const float4*)beta;
    float4 bb[4], mug;
#pragma unroll
    for (int p = 0; p < 4; ++p) bb[p] = B4[(size_t)p * FG4 + gi4];
    mug = ((const float4*)mu)[gi4];
    __syncthreads();

#pragma unroll
    for (int i0 = 0; i0 < 16; i0 += 4) {
        float sy[4], se[4];
#pragma unroll
        for (int j = 0; j < 4; ++j) {
            const int i = i0 + j;
            float4 y = ya[i];
            float4 lu = mug;
#pragma unroll
            for (int p = 0; p < 4; ++p) {
                float xp = Xs[i * 4 + p];
                lu.x = fmaf(xp, bb[p].x, lu.x);
                lu.y = fmaf(xp, bb[p].y, lu.y);
                lu.z = fmaf(xp, bb[p].z, lu.z);
                lu.w = fmaf(xp, bb[p].w, lu.w);
            }
            float e = (__expf(lu.x) + __expf(lu.y)) + (__expf(lu.z) + __expf(lu.w));
            se[j] = active ? e : 0.0f;
            sy[j] = active ? ((y.x + y.y) + (y.z + y.w)) : 0.0f;
        }
#pragma unroll
        for (int off = 32; off; off >>= 1) {
#pragma unroll
            for (int j = 0; j < 4; ++j) {
                sy[j] += __shfl_down(sy[j], off, 64);
                se[j] += __shfl_down(se[j], off, 64);
            }
        }
        if (lane == 0) {
#pragma unroll
            for (int j = 0; j < 4; ++j) {
                syp[wid][i0 + j] = sy[j];
                sep[wid][i0 + j] = se[j];
            }
        }
    }
    __syncthreads();
    if (tid < 16) {
        float a = (syp[0][tid] + syp[1][tid]) + (syp[2][tid] + syp[3][tid]);
        float b = (sep[0][tid] + sep[1][tid]) + (sep[2][tid] + sep[3][tid]);
        atomicAdd(&syw[n0 + tid], a);
        atomicAdd(&sew[n0 + tid], b);
    }
}

// ---------------------------------------------------------------------------
// K2: likelihood. 1280 blocks; batch-8 load issue; LDS lgamma(y+1) table.
// ---------------------------------------------------------------------------
__global__ __launch_bounds__(256, 4) void nb_fast(
        const float* __restrict__ X, const float* __restrict__ Y,
        const float* __restrict__ mu, const float* __restrict__ beta,
        const float* __restrict__ rg, const float* __restrict__ cgw,
        const float* __restrict__ syw, const float* __restrict__ sew,
        double* __restrict__ acc) {
    __shared__ float lgY[512];
    __shared__ float Xs[64];
    __shared__ float dcs[16];
    __shared__ float red[4];

    const int tid  = threadIdx.x;
    const int lane = tid & 63, wid = tid >> 6;
    const int c    = blockIdx.x % FNCH;
    const int s    = blockIdx.x / FNCH;
    const int n0   = s * 16;
    const bool active = (tid < FCH4);
    const int gi4  = c * FCH4 + (active ? tid : FCH4 - 1);

    // batch A: 8 row loads in flight
    const float4* __restrict__ Yp = (const float4*)Y + (size_t)n0 * FG4 + gi4;
    float4 ya[8];
#pragma unroll
    for (int j = 0; j < 8; ++j) ya[j] = Yp[(size_t)j * FG4];

    // stage table/X/dc while loads fly
    for (int i = tid; i < 500; i += 256) lgY[i] = lgamma_pos((float)(i + 1));
    if (tid < 64) Xs[tid] = X[(size_t)n0 * 4 + tid];
    if (tid < 16) dcs[tid] = __logf(syw[n0 + tid]) - __logf(sew[n0 + tid]);

    const float4* __restrict__ B4 = (const float4*)beta;
    float4 bb[4], mug, r4, cg4;
#pragma unroll
    for (int p = 0; p < 4; ++p) bb[p] = B4[(size_t)p * FG4 + gi4];
    mug = ((const float4*)mu)[gi4];
    r4  = ((const float4*)rg)[gi4];
    cg4 = ((const float4*)cgw)[gi4];
    __syncthreads();

    float t0 = 0.0f, t1 = 0.0f, t2 = 0.0f, t3 = 0.0f;
    auto elem = [&](int i, float4 y) {
        float dcn = dcs[i];
        float4 lu = mug;
#pragma unroll
        for (int p = 0; p < 4; ++p) {
            float xp = Xs[i * 4 + p];
            lu.x = fmaf(xp, bb[p].x, lu.x);
            lu.y = fmaf(xp, bb[p].y, lu.y);
            lu.z = fmaf(xp, bb[p].z, lu.z);
            lu.w = fmaf(xp, bb[p].w, lu.w);
        }
        float lm, m, yr;
        lm = dcn + lu.x; m = __expf(lm); yr = y.x + r4.x;
        t0 += stirling_lg(yr) - lgY[__float2int_rz(y.x)]
            + fmaf(y.x, lm, -yr * __logf(r4.x + m)) + cg4.x;
        lm = dcn + lu.y; m = __expf(lm); yr = y.y + r4.y;
        t1 += stirling_lg(yr) - lgY[__float2int_rz(y.y)]
            + fmaf(y.y, lm, -yr * __logf(r4.y + m)) + cg4.y;
        lm = dcn + lu.z; m = __expf(lm); yr = y.z + r4.z;
        t2 += stirling_lg(yr) - lgY[__float2int_rz(y.z)]
            + fmaf(y.z, lm, -yr * __logf(r4.z + m)) + cg4.z;
        lm = dcn + lu.w; m = __expf(lm); yr = y.w + r4.w;
        t3 += stirling_lg(yr) - lgY[__float2int_rz(y.w)]
            + fmaf(y.w, lm, -yr * __logf(r4.w + m)) + cg4.w;
    };

    // issue batch B, then consume A, then consume B
    float4 yb[8];
#pragma unroll
    for (int j = 0; j < 8; ++j) yb[j] = Yp[(size_t)(8 + j) * FG4];
#pragma unroll
    for (int i = 0; i < 8; ++i) elem(i, ya[i]);
#pragma unroll
    for (int i = 0; i < 8; ++i) elem(8 + i, yb[i]);

    float accl = active ? ((t0 + t1) + (t2 + t3)) : 0.0f;
    accl = wave_reduce(accl);
    if (lane == 0) red[wid] = accl;
    __syncthreads();
    if (tid == 0)
        atomicAdd(acc, (double)((red[0] + red[1]) + (red[2] + red[3])));
}

__global__ void finalize_kernel(const double* __restrict__ acc, float* __restrict__ out) {
    out[0] = (float)acc[0];
}

// ---------------------------------------------------------------------------
// Generic fallbacks (correctness only).
// ---------------------------------------------------------------------------
__global__ void row_stats_generic(
        const float* __restrict__ X, const float* __restrict__ Y,
        const float* __restrict__ mu, const float* __restrict__ beta,
        float* __restrict__ syw, float* __restrict__ sew, int N, int P, int G) {
    const int n = blockIdx.x;
    const int tid = threadIdx.x;
    float sy = 0.0f, se = 0.0f;
    for (int g = tid; g < G; g += 256) {
        sy += Y[(size_t)n * G + g];
        float lu = mu[g];
        for (int p = 0; p < P; ++p) lu += X[(size_t)n * P + p] * beta[(size_t)p * G + g];
        se += __expf(lu);
    }
    sy = wave_reduce(sy);
    se = wave_reduce(se);
    __shared__ float r1[4], r2[4];
    int lane = tid & 63, wid = tid >> 6;
    if (lane == 0) { r1[wid] = sy; r2[wid] = se; }
    __syncthreads();
    if (tid == 0) {
        syw[n] = (r1[0] + r1[1]) + (r1[2] + r1[3]);
        sew[n] = (r2[0] + r2[1]) + (r2[2] + r2[3]);
    }
}

__global__ void nb_generic(
        const float* __restrict__ X, const float* __restrict__ Y,
        const float* __restrict__ mu, const float* __restrict__ beta,
        const float* __restrict__ rg, const float* __restrict__ cgw,
        const float* __restrict__ syw, const float* __restrict__ sew,
        double* __restrict__ acc, int N, int P, int G) {
    const int n = blockIdx.x;
    const int tid = threadIdx.x;
    float dcn = __logf(syw[n]) - __logf(sew[n]);
    float accl = 0.0f;
    for (int g = tid; g < G; g += 256) {
        float y = Y[(size_t)n * G + g];
        float lu = mu[g];
        for (int p = 0; p < P; ++p) lu += X[(size_t)n * P + p] * beta[(size_t)p * G + g];
        float lm = dcn + lu;
        float r = rg[g];
        float m = __expf(lm);
        accl += stirling_lg(y + r) - lgamma_pos(y + 1.0f)
                + fmaf(y, lm, -(y + r) * __logf(r + m)) + cgw[g];
    }
    accl = wave_reduce(accl);
    __shared__ float red[4];
    int lane = tid & 63, wid = tid >> 6;
    if (lane == 0) red[wid] = accl;
    __syncthreads();
    if (tid == 0)
        atomicAdd(acc, (double)((red[0] + red[1]) + (red[2] + red[3])));
}

// ---------------------------------------------------------------------------
extern "C" void kernel_launch(void* const* d_in, const int* in_sizes, int n_in,
                              void* d_out, int out_size, void* d_ws, size_t ws_size,
                              hipStream_t stream) {
    const float* X    = (const float*)d_in[0];
    const float* Y    = (const float*)d_in[1];
    const float* mu   = (const float*)d_in[2];
    const float* beta = (const float*)d_in[3];
    const float* phi  = (const float*)d_in[4];
    float* out = (float*)d_out;

    const int G = in_sizes[2];
    const int N = in_sizes[1] / G;
    const int P = in_sizes[0] / N;

    // ws layout: acc@0 | syw@256 [N] | sew@4608 [N] | rg@8960 [G] | cg@8960+4G [G]
    char* ws = (char*)d_ws;
    double* acc = (double*)ws;
    float*  syw = (float*)(ws + 256);
    float*  sew = (float*)(ws + 4608);
    float*  rgw = (float*)(ws + 8960);
    float*  cgw = (float*)(ws + 8960 + (size_t)4 * G);

    hipMemsetAsync(d_ws, 0, 8960, stream);   // acc + syw + sew

    const bool fast_ok = (N == 1024 && G == 20000 && P == 4);
    int gblocks = (G + 255) / 256;

    if (fast_ok) {
        pre_fast<<<FNBLK, 256, 0, stream>>>(X, Y, mu, beta, syw, sew);
        setup_kernel<<<gblocks, 256, 0, stream>>>(mu, beta, phi, acc, rgw, cgw, P, G);
        nb_fast<<<FNBLK, 256, 0, stream>>>(X, Y, mu, beta, rgw, cgw, syw, sew, acc);
    } else {
        setup_kernel<<<gblocks, 256, 0, stream>>>(mu, beta, phi, acc, rgw, cgw, P, G);
        row_stats_generic<<<N, 256, 0, stream>>>(X, Y, mu, beta, syw, sew, N, P, G);
        nb_generic<<<N, 256, 0, stream>>>(X, Y, mu, beta, rgw, cgw, syw, sew,
                                          acc, N, P, G);
    }
    finalize_kernel<<<1, 1, 0, stream>>>(acc, out);
}